// Round 6
// baseline (251.355 us; speedup 1.0000x reference)
//
#include <hip/hip_runtime.h>

#define BINS  30
#define NROWS 8192
#define NCOLS 2048
#define COLS_PER_BLK 256                 // grid.x = 8
#define ROWS_PER_BLK 128                 // grid.y = 64

#define FIXED_SCALE 16777216.0f          // 2^24 fixed point for bce
#define CNT_SHIFT   50
#define SUM_MASK    ((1ull << CNT_SHIFT) - 1)

// ws layout (bytes):
//   g_pack   : u64[BINS][NCOLS]   [0, 491520)   <- memset to 0 each launch
//   blockPart: float[8]           [491520, +32)  <- plain-stored, no init
#define WS_GPACK 0
#define WS_BPART (BINS * NCOLS * 8)

// ---------------------------------------------------------------------------
// Kernel A: one pass over preds/targets.
// Block = 256 cols x 128 rows (grid 8x64 = 512 blocks, 1024 thr, 2 blk/CU).
// Lane l owns cols 4l..4l+3  -> a wave covers 256 DISTINCT columns, so
// ds_add_u64 never hits the same address twice in one instruction.
// LDS h[b][j][l] (60 KB): bank = (2l)%32 -> 2-way aliasing only (free).
// Loads: two batches of 4 rows; each batch issues 4 float4 + 4 int4 loads
// back-to-back with no intervening consumer -> 8 loads in flight (real MLP).
// Packed cell: count in bits [50:63], bce*2^24 in [0:50).
//   global max count/cell = 8192 < 2^14; max sum = 8192*6.4*2^24 < 2^41.
// Flush: global u64 atomics straight into g_pack (no partials, no k_reduce).
// ---------------------------------------------------------------------------
__global__ __launch_bounds__(1024, 8) void k_main(
    const float* __restrict__ preds, const int* __restrict__ targets,
    unsigned long long* __restrict__ g_pack)
{
    __shared__ unsigned long long h[BINS * COLS_PER_BLK];   // 61440 B
    const int tid = threadIdx.x;
    for (int i = tid; i < BINS * COLS_PER_BLK; i += 1024) h[i] = 0ull;
    __syncthreads();

    const int wave = tid >> 6;
    const int lane = tid & 63;
    const int colBase = blockIdx.x * COLS_PER_BLK;
    const int col0 = colBase + 4 * lane;
    const int r0   = blockIdx.y * ROWS_PER_BLK + wave * 8;   // 8 rows/thread

    const float4* P = (const float4*)(preds   + (size_t)r0 * NCOLS + col0);
    const int4*   T = (const int4*)  (targets + (size_t)r0 * NCOLS + col0);
    const int RV = NCOLS / 4;   // one row in float4 units

    #pragma unroll
    for (int batch = 0; batch < 2; ++batch) {
        // 8 loads, no consumer in between -> all in flight
        float4 p0 = P[0], p1 = P[RV], p2 = P[2 * RV], p3 = P[3 * RV];
        int4   t0 = T[0], t1 = T[RV], t2 = T[2 * RV], t3 = T[3 * RV];
        P += 4 * RV; T += 4 * RV;

        const float4 pb[4] = {p0, p1, p2, p3};
        const int4   tb[4] = {t0, t1, t2, t3};
        #pragma unroll
        for (int q = 0; q < 4; ++q) {
            const float pv[4] = {pb[q].x, pb[q].y, pb[q].z, pb[q].w};
            const int   tv[4] = {tb[q].x, tb[q].y, tb[q].z, tb[q].w};
            #pragma unroll
            for (int j = 0; j < 4; ++j) {
                float p  = pv[j];
                float pp = tv[j] ? -p : p;                    // p'
                float e  = __expf(-fabsf(pp));                // exp(-|p'|)
                float d  = 1.0f + e;
                float r1 = __builtin_amdgcn_rcpf(d);
                float g  = (pp >= 0.0f) ? r1 : e * r1;        // sigmoid(p') = g
                int   b  = (int)(g * 30.0f);
                b = b > (BINS - 1) ? (BINS - 1) : b;
                float bce = fmaxf(pp, 0.0f) + __logf(d);      // softplus(p')
                unsigned long long pk = (1ull << CNT_SHIFT)
                    | (unsigned long long)(bce * FIXED_SCALE + 0.5f);
                atomicAdd(&h[b * COLS_PER_BLK + (j << 6) + lane], pk);
            }
        }
    }
    __syncthreads();

    // flush nonzero cells to global packed table (unswizzle: col = 4l + j)
    for (int i = tid; i < BINS * COLS_PER_BLK; i += 1024) {
        const unsigned long long v = h[i];
        if (v) {
            const int b = i >> 8;          // /256
            const int r = i & 255;
            const int j = r >> 6;
            const int l = r & 63;
            atomicAdd(&g_pack[(size_t)b * NCOLS + colBase + 4 * l + j], v);
        }
    }
}

// ---------------------------------------------------------------------------
// Kernel B: per-column contraction of the packed table.
// col c contributes (1/(n_c*NCOLS)) * sum_b S[b,c]/acc_new[b,c],
//   acc_new = 0.75*acc_sum + 0.25*count.
// 8 blocks x 256 threads; block partial plain-stored to blockPart.
// ---------------------------------------------------------------------------
__global__ __launch_bounds__(256) void k_colsum(
    const unsigned long long* __restrict__ g_pack,
    const float* __restrict__ acc_sum, float* __restrict__ blockPart)
{
    __shared__ float wave_sums[4];
    const int tid = threadIdx.x;
    const int c   = blockIdx.x * 256 + tid;

    float colsum = 0.0f;
    int n = 0;
    #pragma unroll
    for (int b = 0; b < BINS; ++b) {
        const size_t gidx = (size_t)b * NCOLS + c;
        const unsigned long long v = g_pack[gidx];
        if (v) {                                   // v!=0 <=> count>=1
            n += 1;
            float cnt = (float)(unsigned)(v >> CNT_SHIFT);
            float s   = (float)(v & SUM_MASK) * (1.0f / FIXED_SCALE);
            float acc_new = 0.75f * acc_sum[gidx] + 0.25f * cnt;
            colsum += s / acc_new;
        }
    }
    colsum /= (float)((n > 1 ? n : 1) * NCOLS);

    #pragma unroll
    for (int off = 32; off > 0; off >>= 1)
        colsum += __shfl_down(colsum, off, 64);
    if ((tid & 63) == 0) wave_sums[tid >> 6] = colsum;
    __syncthreads();
    if (tid == 0)
        blockPart[blockIdx.x] = wave_sums[0] + wave_sums[1] + wave_sums[2] + wave_sums[3];
}

__global__ void k_final(const float* __restrict__ blockPart, float* __restrict__ out)
{
    double s = 0.0;
    #pragma unroll
    for (int i = 0; i < 8; ++i) s += (double)blockPart[i];
    out[0] = (float)s;
}

extern "C" void kernel_launch(void* const* d_in, const int* in_sizes, int n_in,
                              void* d_out, int out_size, void* d_ws, size_t ws_size,
                              hipStream_t stream)
{
    const float* preds   = (const float*)d_in[0];
    const int*   targets = (const int*)d_in[1];
    const float* acc_sum = (const float*)d_in[2];

    unsigned long long* g_pack = (unsigned long long*)((char*)d_ws + WS_GPACK);
    float* blockPart           = (float*)((char*)d_ws + WS_BPART);

    hipMemsetAsync(g_pack, 0, BINS * NCOLS * 8, stream);

    dim3 gA(NCOLS / COLS_PER_BLK, NROWS / ROWS_PER_BLK);   // (8, 64) = 512 blocks
    k_main<<<gA, 1024, 0, stream>>>(preds, targets, g_pack);

    k_colsum<<<NCOLS / 256, 256, 0, stream>>>(g_pack, acc_sum, blockPart);

    k_final<<<1, 1, 0, stream>>>(blockPart, (float*)d_out);
}

// Round 7
// 243.673 us; speedup vs baseline: 1.0315x; 1.0315x over previous
//
#include <hip/hip_runtime.h>

#define BINS  30
#define NROWS 8192
#define NCOLS 2048
#define COLS_PER_BLK 256                 // grid.x = 8
#define ROWS_PER_BLK 256                 // grid.y = 32
#define YSLICES 32

#define FIXED_SCALE 16777216.0f          // 2^24 fixed point for bce
#define CNT_SHIFT   50
#define SUM_MASK    ((1ull << CNT_SHIFT) - 1)

// ws layout (bytes), all plain-stored before read -> no zeroing needed:
//   part    : u64[YSLICES][BINS][NCOLS]   (15.7 MB)
//   blockPart: float[8]
#define WS_PART  0
#define WS_BPART (YSLICES * BINS * NCOLS * 8)

// ---------------------------------------------------------------------------
// Kernel A: one pass over preds/targets.
// Grid (8,32) = 256 blocks (exactly 1/CU), 1024 threads, 60 KB LDS.
// Lane l owns cols 4l..4l+3 -> every ds_add_u64 hits 64 DISTINCT addresses
// (zero same-address serialization); bank = (2l)%32 -> 2-way only (free).
// MLP: 4 batches of 4 rows; next batch's 8 loads (4 float4 + 4 int4) are
// issued, then __builtin_amdgcn_sched_barrier(0) pins them BEFORE the
// current batch's compute -> ~8 loads in flight per wave (vmcnt(8) overlap).
// Packed LDS cell: count in bits [50:63], bce*2^24 in [0:50).
// Flush: coalesced plain u64 stores of the block's private slice.
// ---------------------------------------------------------------------------
__global__ __launch_bounds__(1024, 4) void k_main(
    const float* __restrict__ preds, const int* __restrict__ targets,
    unsigned long long* __restrict__ part)
{
    __shared__ unsigned long long h[BINS * COLS_PER_BLK];   // 61440 B
    const int tid = threadIdx.x;
    for (int i = tid; i < BINS * COLS_PER_BLK; i += 1024) h[i] = 0ull;
    __syncthreads();

    const int wave = tid >> 6;
    const int lane = tid & 63;
    const int colBase = blockIdx.x * COLS_PER_BLK;
    const int col0 = colBase + 4 * lane;
    const int r0   = blockIdx.y * ROWS_PER_BLK + wave * 16;  // 16 rows/wave

    const float4* P = (const float4*)(preds   + (size_t)r0 * NCOLS + col0);
    const int4*   T = (const int4*)  (targets + (size_t)r0 * NCOLS + col0);
    const int RV = NCOLS / 4;        // one row in float4 units

    // prologue: batch 0 in flight
    float4 pc0 = P[0], pc1 = P[RV], pc2 = P[2 * RV], pc3 = P[3 * RV];
    int4   tc0 = T[0], tc1 = T[RV], tc2 = T[2 * RV], tc3 = T[3 * RV];

    #pragma unroll
    for (int q = 0; q < 4; ++q) {
        float4 pn0, pn1, pn2, pn3;
        int4   tn0, tn1, tn2, tn3;
        if (q < 3) {
            P += 4 * RV; T += 4 * RV;
            pn0 = P[0]; pn1 = P[RV]; pn2 = P[2 * RV]; pn3 = P[3 * RV];
            tn0 = T[0]; tn1 = T[RV]; tn2 = T[2 * RV]; tn3 = T[3 * RV];
        }
        __builtin_amdgcn_sched_barrier(0);   // loads above may NOT sink below

        const float4 pb[4] = {pc0, pc1, pc2, pc3};
        const int4   tb[4] = {tc0, tc1, tc2, tc3};
        #pragma unroll
        for (int r = 0; r < 4; ++r) {
            const float pv[4] = {pb[r].x, pb[r].y, pb[r].z, pb[r].w};
            const int   tv[4] = {tb[r].x, tb[r].y, tb[r].z, tb[r].w};
            #pragma unroll
            for (int j = 0; j < 4; ++j) {
                float p  = pv[j];
                float pp = tv[j] ? -p : p;                    // p'
                float e  = __expf(-fabsf(pp));                // exp(-|p'|)
                float d  = 1.0f + e;
                float r1 = __builtin_amdgcn_rcpf(d);
                float g  = (pp >= 0.0f) ? r1 : e * r1;        // sigmoid(p')
                int   b  = (int)(g * 30.0f);
                b = b > (BINS - 1) ? (BINS - 1) : b;
                float bce = fmaxf(pp, 0.0f) + __logf(d);      // softplus(p')
                unsigned long long pk = (1ull << CNT_SHIFT)
                    | (unsigned long long)(bce * FIXED_SCALE + 0.5f);
                atomicAdd(&h[b * COLS_PER_BLK + (j << 6) + lane], pk);
            }
        }
        pc0 = pn0; pc1 = pn1; pc2 = pn2; pc3 = pn3;
        tc0 = tn0; tc1 = tn1; tc2 = tn2; tc3 = tn3;
    }
    __syncthreads();

    // flush: part[y][b][colBase + r], r = tid&255, coalesced u64 stores.
    // LDS cell for (b, col=4l+j) is h[b*256 + j*64 + l].
    const size_t outBase = (size_t)blockIdx.y * BINS * NCOLS + colBase;
    for (int i = tid; i < BINS * COLS_PER_BLK; i += 1024) {
        const int b = i >> 8;
        const int r = i & 255;
        const int l = r >> 2;
        const int j = r & 3;
        part[outBase + (size_t)b * NCOLS + r] = h[b * COLS_PER_BLK + (j << 6) + l];
    }
}

// ---------------------------------------------------------------------------
// Kernel B: reduce 32 slices + per-column contraction, fused.
// 8 blocks x 256 threads; thread c sums part[y][b][c] over y (coalesced),
// then colsum += S/acc_new per nonempty bin; /(n*NCOLS); block-reduce.
// ---------------------------------------------------------------------------
__global__ __launch_bounds__(256) void k_sum(
    const unsigned long long* __restrict__ part,
    const float* __restrict__ acc_sum, float* __restrict__ blockPart)
{
    __shared__ float wave_sums[4];
    const int tid = threadIdx.x;
    const int c   = blockIdx.x * 256 + tid;

    float colsum = 0.0f;
    int n = 0;
    #pragma unroll
    for (int b = 0; b < BINS; ++b) {
        unsigned long long v = 0ull;
        #pragma unroll 8
        for (int y = 0; y < YSLICES; ++y)
            v += part[((size_t)y * BINS + b) * NCOLS + c];
        if (v) {                                  // v!=0 <=> count>=1
            n += 1;
            float cnt = (float)(unsigned)(v >> CNT_SHIFT);
            float s   = (float)(v & SUM_MASK) * (1.0f / FIXED_SCALE);
            float acc_new = 0.75f * acc_sum[(size_t)b * NCOLS + c] + 0.25f * cnt;
            colsum += s / acc_new;
        }
    }
    colsum /= (float)((n > 1 ? n : 1) * NCOLS);

    #pragma unroll
    for (int off = 32; off > 0; off >>= 1)
        colsum += __shfl_down(colsum, off, 64);
    if ((tid & 63) == 0) wave_sums[tid >> 6] = colsum;
    __syncthreads();
    if (tid == 0)
        blockPart[blockIdx.x] = wave_sums[0] + wave_sums[1] + wave_sums[2] + wave_sums[3];
}

__global__ void k_final(const float* __restrict__ blockPart, float* __restrict__ out)
{
    double s = 0.0;
    #pragma unroll
    for (int i = 0; i < 8; ++i) s += (double)blockPart[i];
    out[0] = (float)s;
}

extern "C" void kernel_launch(void* const* d_in, const int* in_sizes, int n_in,
                              void* d_out, int out_size, void* d_ws, size_t ws_size,
                              hipStream_t stream)
{
    const float* preds   = (const float*)d_in[0];
    const int*   targets = (const int*)d_in[1];
    const float* acc_sum = (const float*)d_in[2];

    unsigned long long* part = (unsigned long long*)((char*)d_ws + WS_PART);
    float* blockPart         = (float*)((char*)d_ws + WS_BPART);

    dim3 gA(NCOLS / COLS_PER_BLK, NROWS / ROWS_PER_BLK);   // (8, 32) = 256 blocks
    k_main<<<gA, 1024, 0, stream>>>(preds, targets, part);

    k_sum<<<NCOLS / 256, 256, 0, stream>>>(part, acc_sum, blockPart);

    k_final<<<1, 1, 0, stream>>>(blockPart, (float*)d_out);
}

// Round 8
// 181.511 us; speedup vs baseline: 1.3848x; 1.3425x over previous
//
#include <hip/hip_runtime.h>

#define BINS  30
#define NROWS 8192
#define NCOLS 2048
#define COLS_PER_BLK 256                 // grid.x = 8
#define ROWS_PER_BLK 256                 // grid.y = 32
#define YSLICES 32

#define FIXED_SCALE 16777216.0f          // 2^24 fixed point for bce
#define CNT_SHIFT   50
#define SUM_MASK    ((1ull << CNT_SHIFT) - 1)

// ws layout (bytes), all plain-stored before read -> no zeroing needed:
//   part : u64[YSLICES][BINS][NCOLS]   (15.7 MB)
//   red  : u64[BINS][NCOLS]            (0.5 MB)
//   blockPart: float[8]
#define WS_PART  0
#define WS_RED   (YSLICES * BINS * NCOLS * 8)
#define WS_BPART (WS_RED + BINS * NCOLS * 8)

// ---------------------------------------------------------------------------
// Kernel A (unchanged from R7 — measured ~25-30 us): one pass over inputs.
// Grid (8,32) = 256 blocks (1/CU), 1024 threads, 60 KB LDS.
// Lane l owns cols 4l..4l+3 -> ds_add_u64 hits 64 DISTINCT addresses
// (zero same-address serialization); bank = (2l)%32 -> 2-way only (free).
// MLP: next batch's 8 loads issued, then sched_barrier(0) pins them before
// the current batch's compute -> ~8 loads in flight per wave.
// Packed LDS cell: count in bits [50:63], bce*2^24 in [0:50).
// ---------------------------------------------------------------------------
__global__ __launch_bounds__(1024, 4) void k_main(
    const float* __restrict__ preds, const int* __restrict__ targets,
    unsigned long long* __restrict__ part)
{
    __shared__ unsigned long long h[BINS * COLS_PER_BLK];   // 61440 B
    const int tid = threadIdx.x;
    for (int i = tid; i < BINS * COLS_PER_BLK; i += 1024) h[i] = 0ull;
    __syncthreads();

    const int wave = tid >> 6;
    const int lane = tid & 63;
    const int colBase = blockIdx.x * COLS_PER_BLK;
    const int col0 = colBase + 4 * lane;
    const int r0   = blockIdx.y * ROWS_PER_BLK + wave * 16;  // 16 rows/wave

    const float4* P = (const float4*)(preds   + (size_t)r0 * NCOLS + col0);
    const int4*   T = (const int4*)  (targets + (size_t)r0 * NCOLS + col0);
    const int RV = NCOLS / 4;        // one row in float4 units

    // prologue: batch 0 in flight
    float4 pc0 = P[0], pc1 = P[RV], pc2 = P[2 * RV], pc3 = P[3 * RV];
    int4   tc0 = T[0], tc1 = T[RV], tc2 = T[2 * RV], tc3 = T[3 * RV];

    #pragma unroll
    for (int q = 0; q < 4; ++q) {
        float4 pn0, pn1, pn2, pn3;
        int4   tn0, tn1, tn2, tn3;
        if (q < 3) {
            P += 4 * RV; T += 4 * RV;
            pn0 = P[0]; pn1 = P[RV]; pn2 = P[2 * RV]; pn3 = P[3 * RV];
            tn0 = T[0]; tn1 = T[RV]; tn2 = T[2 * RV]; tn3 = T[3 * RV];
        }
        __builtin_amdgcn_sched_barrier(0);   // loads above may NOT sink below

        const float4 pb[4] = {pc0, pc1, pc2, pc3};
        const int4   tb[4] = {tc0, tc1, tc2, tc3};
        #pragma unroll
        for (int r = 0; r < 4; ++r) {
            const float pv[4] = {pb[r].x, pb[r].y, pb[r].z, pb[r].w};
            const int   tv[4] = {tb[r].x, tb[r].y, tb[r].z, tb[r].w};
            #pragma unroll
            for (int j = 0; j < 4; ++j) {
                float p  = pv[j];
                float pp = tv[j] ? -p : p;                    // p'
                float e  = __expf(-fabsf(pp));                // exp(-|p'|)
                float d  = 1.0f + e;
                float r1 = __builtin_amdgcn_rcpf(d);
                float g  = (pp >= 0.0f) ? r1 : e * r1;        // sigmoid(p')
                int   b  = (int)(g * 30.0f);
                b = b > (BINS - 1) ? (BINS - 1) : b;
                float bce = fmaxf(pp, 0.0f) + __logf(d);      // softplus(p')
                unsigned long long pk = (1ull << CNT_SHIFT)
                    | (unsigned long long)(bce * FIXED_SCALE + 0.5f);
                atomicAdd(&h[b * COLS_PER_BLK + (j << 6) + lane], pk);
            }
        }
        pc0 = pn0; pc1 = pn1; pc2 = pn2; pc3 = pn3;
        tc0 = tn0; tc1 = tn1; tc2 = tn2; tc3 = tn3;
    }
    __syncthreads();

    // flush: part[y][b][colBase + r], coalesced u64 stores (unswizzle col=4l+j)
    const size_t outBase = (size_t)blockIdx.y * BINS * NCOLS + colBase;
    for (int i = tid; i < BINS * COLS_PER_BLK; i += 1024) {
        const int b = i >> 8;
        const int r = i & 255;
        const int l = r >> 2;
        const int j = r & 3;
        part[outBase + (size_t)b * NCOLS + r] = h[b * COLS_PER_BLK + (j << 6) + l];
    }
}

// ---------------------------------------------------------------------------
// Kernel B: WIDE y-slice reduction (fixes R7's 8-block latency disaster).
// 120 blocks x 256 threads; each thread owns 2 adjacent cells -> ulonglong2
// (16B/lane, coalesced). 32 independent loads deep -> full MLP.
// ---------------------------------------------------------------------------
__global__ __launch_bounds__(256) void k_reduce(
    const unsigned long long* __restrict__ part, unsigned long long* __restrict__ red)
{
    const int id = blockIdx.x * 256 + threadIdx.x;    // 0 .. 30719
    const size_t cell = (size_t)id * 2;
    unsigned long long a = 0ull, b = 0ull;
    #pragma unroll 8
    for (int y = 0; y < YSLICES; ++y) {
        const ulonglong2 v = *(const ulonglong2*)(part + (size_t)y * BINS * NCOLS + cell);
        a += v.x; b += v.y;
    }
    ulonglong2* o = (ulonglong2*)(red + cell);
    *o = make_ulonglong2(a, b);
}

// ---------------------------------------------------------------------------
// Kernel C: per-column contraction of the reduced 30x2048 table (0.5 MB).
// col c contributes (1/(n_c*NCOLS)) * sum_b S[b,c]/acc_new[b,c].
// ---------------------------------------------------------------------------
__global__ __launch_bounds__(256) void k_colsum(
    const unsigned long long* __restrict__ red,
    const float* __restrict__ acc_sum, float* __restrict__ blockPart)
{
    __shared__ float wave_sums[4];
    const int tid = threadIdx.x;
    const int c   = blockIdx.x * 256 + tid;

    float colsum = 0.0f;
    int n = 0;
    #pragma unroll
    for (int b = 0; b < BINS; ++b) {
        const size_t gidx = (size_t)b * NCOLS + c;
        const unsigned long long v = red[gidx];
        if (v) {                                   // v!=0 <=> count>=1
            n += 1;
            float cnt = (float)(unsigned)(v >> CNT_SHIFT);
            float s   = (float)(v & SUM_MASK) * (1.0f / FIXED_SCALE);
            float acc_new = 0.75f * acc_sum[gidx] + 0.25f * cnt;
            colsum += s / acc_new;
        }
    }
    colsum /= (float)((n > 1 ? n : 1) * NCOLS);

    #pragma unroll
    for (int off = 32; off > 0; off >>= 1)
        colsum += __shfl_down(colsum, off, 64);
    if ((tid & 63) == 0) wave_sums[tid >> 6] = colsum;
    __syncthreads();
    if (tid == 0)
        blockPart[blockIdx.x] = wave_sums[0] + wave_sums[1] + wave_sums[2] + wave_sums[3];
}

__global__ void k_final(const float* __restrict__ blockPart, float* __restrict__ out)
{
    double s = 0.0;
    #pragma unroll
    for (int i = 0; i < 8; ++i) s += (double)blockPart[i];
    out[0] = (float)s;
}

extern "C" void kernel_launch(void* const* d_in, const int* in_sizes, int n_in,
                              void* d_out, int out_size, void* d_ws, size_t ws_size,
                              hipStream_t stream)
{
    const float* preds   = (const float*)d_in[0];
    const int*   targets = (const int*)d_in[1];
    const float* acc_sum = (const float*)d_in[2];

    unsigned long long* part = (unsigned long long*)((char*)d_ws + WS_PART);
    unsigned long long* red  = (unsigned long long*)((char*)d_ws + WS_RED);
    float* blockPart         = (float*)((char*)d_ws + WS_BPART);

    dim3 gA(NCOLS / COLS_PER_BLK, NROWS / ROWS_PER_BLK);   // (8, 32) = 256 blocks
    k_main<<<gA, 1024, 0, stream>>>(preds, targets, part);

    k_reduce<<<(BINS * NCOLS / 2) / 256, 256, 0, stream>>>(part, red);

    k_colsum<<<NCOLS / 256, 256, 0, stream>>>(red, acc_sum, blockPart);

    k_final<<<1, 1, 0, stream>>>(blockPart, (float*)d_out);
}

// Round 9
// 179.608 us; speedup vs baseline: 1.3995x; 1.0106x over previous
//
#include <hip/hip_runtime.h>

#define BINS  30
#define NROWS 8192
#define NCOLS 2048
#define COLS_PER_BLK 256                 // grid.x = 8
#define ROWS_PER_BLK 128                 // grid.y = 64
#define YSLICES 64

#define FIXED_SCALE 16384.0f             // 2^14 fixed point for bce
#define CNT_SHIFT   24                   // count in bits [24:31], sum in [0:24)
#define SUM_MASK    ((1u << CNT_SHIFT) - 1)

// ws layout (bytes), all plain-stored before read -> no zeroing needed:
//   part : u32[YSLICES][BINS][NCOLS]   (15.7 MB)
//   cnt  : float[BINS][NCOLS]          (245760 B)
//   bsum : float[BINS][NCOLS]          (245760 B)
//   blockPart: float[8]
#define WS_PART  0
#define WS_CNT   (YSLICES * BINS * NCOLS * 4)
#define WS_BSUM  (WS_CNT + BINS * NCOLS * 4)
#define WS_BPART (WS_BSUM + BINS * NCOLS * 4)

// ---------------------------------------------------------------------------
// Kernel A: one pass over preds/targets.
// Grid (8,64) = 512 blocks, 1024 threads, 30 KB LDS -> 2 blocks/CU,
// 32 waves/CU (fixes R8's 1-block/CU occupancy halving).
// Packed u32 LDS cell: count in [24:31] (max 128/cell/block), bce*2^14 in
// [0:24) (max 128*6.4*2^14 = 13.4M < 2^24, no carry).
// ds_add_u32: lane l owns 4 DISTINCT cols -> 64 distinct addresses/instr
// (zero same-address serialization); bank = lane%32 -> 2-way only (free).
// MLP: depth-2 batches of 2 rows (2 float4 + 2 int4 in flight), pinned by
// sched_barrier(0); ~55 VGPR fits the 64-cap from __launch_bounds__(1024,8)
// so 2 blocks/CU actually materializes.
// ---------------------------------------------------------------------------
__global__ __launch_bounds__(1024, 8) void k_main(
    const float* __restrict__ preds, const int* __restrict__ targets,
    unsigned int* __restrict__ part)
{
    __shared__ unsigned int h[BINS * COLS_PER_BLK];   // 30720 B
    const int tid = threadIdx.x;
    for (int i = tid; i < BINS * COLS_PER_BLK; i += 1024) h[i] = 0u;
    __syncthreads();

    const int wave = tid >> 6;
    const int lane = tid & 63;
    const int colBase = blockIdx.x * COLS_PER_BLK;
    const int col0 = colBase + 4 * lane;
    const int r0   = blockIdx.y * ROWS_PER_BLK + wave * 8;   // 8 rows/wave

    const float4* P = (const float4*)(preds   + (size_t)r0 * NCOLS + col0);
    const int4*   T = (const int4*)  (targets + (size_t)r0 * NCOLS + col0);
    const int RV = NCOLS / 4;        // one row in float4 units

    // prologue: batch 0 (rows 0,1) in flight
    float4 pc0 = P[0], pc1 = P[RV];
    int4   tc0 = T[0], tc1 = T[RV];

    #pragma unroll
    for (int q = 0; q < 4; ++q) {
        float4 pn0, pn1;
        int4   tn0, tn1;
        if (q < 3) {
            P += 2 * RV; T += 2 * RV;
            pn0 = P[0]; pn1 = P[RV];
            tn0 = T[0]; tn1 = T[RV];
        }
        __builtin_amdgcn_sched_barrier(0);   // loads above may NOT sink below

        const float4 pb[2] = {pc0, pc1};
        const int4   tb[2] = {tc0, tc1};
        #pragma unroll
        for (int r = 0; r < 2; ++r) {
            const float pv[4] = {pb[r].x, pb[r].y, pb[r].z, pb[r].w};
            const int   tv[4] = {tb[r].x, tb[r].y, tb[r].z, tb[r].w};
            #pragma unroll
            for (int j = 0; j < 4; ++j) {
                float p  = pv[j];
                float pp = tv[j] ? -p : p;                    // p'
                float e  = __expf(-fabsf(pp));                // exp(-|p'|)
                float d  = 1.0f + e;
                float r1 = __builtin_amdgcn_rcpf(d);
                float g  = (pp >= 0.0f) ? r1 : e * r1;        // sigmoid(p')
                int   b  = (int)(g * 30.0f);
                b = b > (BINS - 1) ? (BINS - 1) : b;
                float bce = fmaxf(pp, 0.0f) + __logf(d);      // softplus(p')
                unsigned int pk = (1u << CNT_SHIFT)
                    | (unsigned int)(bce * FIXED_SCALE + 0.5f);
                atomicAdd(&h[b * COLS_PER_BLK + (j << 6) + lane], pk);
            }
        }
        pc0 = pn0; pc1 = pn1;
        tc0 = tn0; tc1 = tn1;
    }
    __syncthreads();

    // flush: part[y][b][colBase + r], coalesced u32 stores (unswizzle col=4l+j)
    const size_t outBase = (size_t)blockIdx.y * BINS * NCOLS + colBase;
    for (int i = tid; i < BINS * COLS_PER_BLK; i += 1024) {
        const int b = i >> 8;
        const int r = i & 255;
        const int l = r >> 2;
        const int j = r & 3;
        part[outBase + (size_t)b * NCOLS + r] = h[b * COLS_PER_BLK + (j << 6) + l];
    }
}

// ---------------------------------------------------------------------------
// Kernel B: wide y-slice reduction with unpack.
// 240 blocks x 256 threads; thread owns one (b,c) cell, sums 64 slices
// (coalesced across threads), writes float count + float bceSum.
// ---------------------------------------------------------------------------
__global__ __launch_bounds__(256) void k_reduce(
    const unsigned int* __restrict__ part,
    float* __restrict__ cnt_f, float* __restrict__ bsum_f)
{
    const int id = blockIdx.x * 256 + threadIdx.x;    // 0 .. 61439
    unsigned int cnt = 0u, sm = 0u;
    #pragma unroll 16
    for (int y = 0; y < YSLICES; ++y) {
        const unsigned int v = part[(size_t)y * BINS * NCOLS + id];
        cnt += v >> CNT_SHIFT;
        sm  += v & SUM_MASK;
    }
    cnt_f[id]  = (float)cnt;
    bsum_f[id] = (float)sm * (1.0f / FIXED_SCALE);
}

// ---------------------------------------------------------------------------
// Kernel C: per-column contraction of the reduced 30x2048 table.
// col c contributes (1/(n_c*NCOLS)) * sum_b S[b,c]/acc_new[b,c].
// ---------------------------------------------------------------------------
__global__ __launch_bounds__(256) void k_colsum(
    const float* __restrict__ cnt_f, const float* __restrict__ bsum_f,
    const float* __restrict__ acc_sum, float* __restrict__ blockPart)
{
    __shared__ float wave_sums[4];
    const int tid = threadIdx.x;
    const int c   = blockIdx.x * 256 + tid;

    float colsum = 0.0f;
    int n = 0;
    #pragma unroll
    for (int b = 0; b < BINS; ++b) {
        const size_t gidx = (size_t)b * NCOLS + c;
        const float cnt = cnt_f[gidx];
        if (cnt >= 1.0f) {
            n += 1;
            float acc_new = 0.75f * acc_sum[gidx] + 0.25f * cnt;
            colsum += bsum_f[gidx] / acc_new;
        }
    }
    colsum /= (float)((n > 1 ? n : 1) * NCOLS);

    #pragma unroll
    for (int off = 32; off > 0; off >>= 1)
        colsum += __shfl_down(colsum, off, 64);
    if ((tid & 63) == 0) wave_sums[tid >> 6] = colsum;
    __syncthreads();
    if (tid == 0)
        blockPart[blockIdx.x] = wave_sums[0] + wave_sums[1] + wave_sums[2] + wave_sums[3];
}

__global__ void k_final(const float* __restrict__ blockPart, float* __restrict__ out)
{
    double s = 0.0;
    #pragma unroll
    for (int i = 0; i < 8; ++i) s += (double)blockPart[i];
    out[0] = (float)s;
}

extern "C" void kernel_launch(void* const* d_in, const int* in_sizes, int n_in,
                              void* d_out, int out_size, void* d_ws, size_t ws_size,
                              hipStream_t stream)
{
    const float* preds   = (const float*)d_in[0];
    const int*   targets = (const int*)d_in[1];
    const float* acc_sum = (const float*)d_in[2];

    unsigned int* part = (unsigned int*)((char*)d_ws + WS_PART);
    float* cnt_f       = (float*)((char*)d_ws + WS_CNT);
    float* bsum_f      = (float*)((char*)d_ws + WS_BSUM);
    float* blockPart   = (float*)((char*)d_ws + WS_BPART);

    dim3 gA(NCOLS / COLS_PER_BLK, NROWS / ROWS_PER_BLK);   // (8, 64) = 512 blocks
    k_main<<<gA, 1024, 0, stream>>>(preds, targets, part);

    k_reduce<<<(BINS * NCOLS) / 256, 256, 0, stream>>>(part, cnt_f, bsum_f);

    k_colsum<<<NCOLS / 256, 256, 0, stream>>>(cnt_f, bsum_f, acc_sum, blockPart);

    k_final<<<1, 1, 0, stream>>>(blockPart, (float*)d_out);
}